// Round 1
// baseline (110.490 us; speedup 1.0000x reference)
//
#include <hip/hip_runtime.h>
#include <hip/hip_bf16.h>

typedef __bf16 bf8_t __attribute__((ext_vector_type(8)));
typedef float  f4_t  __attribute__((ext_vector_type(4)));

constexpr int Bc = 2;
constexpr int Tc = 2048;
constexpr int Sc = 2048;
constexpr int Hc = 8;
constexpr int Dc = 64;
constexpr int BQ = 64;          // Q rows per block
constexpr int BK = 32;          // keys per tile
constexpr int nQB = Tc / BQ;    // 32
constexpr int NKT = Sc / BK;    // 64 key tiles per (b,h)
constexpr int TILE_H = 4096;    // halves per staged tile: K 2048 + V^T 2048 (8 KB)
constexpr int LDP = BK + 4;     // Ps row stride

__device__ __forceinline__ void g2l16(const void* g, void* l) {
    __builtin_amdgcn_global_load_lds(
        (const __attribute__((address_space(1))) void*)g,
        (__attribute__((address_space(3))) void*)l, 16, 0, 0);
}

// Kernel 0: one-shot fp32->bf16 convert + V-transpose + XOR-swizzle into
// per-tile 8KB "LDS images": kvb[(b*8+h)*64 + s32] =
//   [ K  rows s(32) x d(64), col halves ^ ((row&7)<<3) ]   (2048 halves)
//   [ V^T rows d(64) x s(32), col halves ^ ((row&3)<<3) ]  (2048 halves)
__global__ __launch_bounds__(256)
void fa_prep(const float* __restrict__ kv, __bf16* __restrict__ kvb)
{
    const int idx    = blockIdx.x * 256 + threadIdx.x;   // 0..524287
    const int tile   = idx >> 9;                         // (b*8+h)*64 + s32
    const int within = idx & 511;                        // 16B chunk in tile
    const int b  = tile >> 9;
    const int h  = (tile >> 6) & 7;
    const int s0 = (tile & 63) * BK;
    __bf16* dst = kvb + (size_t)tile * TILE_H + within * 8;
    bf8_t o;
    if (within < 256) {                                  // K region
        const int row = within >> 3;                     // key in tile
        const int col = ((within & 7) * 8) ^ ((row & 7) << 3);
        const float* src = kv + (((size_t)(b * Sc + s0 + row) * 2 + 0) * Hc + h) * Dc + col;
        const float4 x0 = *(const float4*)src;
        const float4 x1 = *(const float4*)(src + 4);
        o[0] = (__bf16)x0.x; o[1] = (__bf16)x0.y; o[2] = (__bf16)x0.z; o[3] = (__bf16)x0.w;
        o[4] = (__bf16)x1.x; o[5] = (__bf16)x1.y; o[6] = (__bf16)x1.z; o[7] = (__bf16)x1.w;
    } else {                                             // V^T region (gather)
        const int c    = within - 256;
        const int vrow = c >> 2;                         // d
        const int sc0  = ((c & 3) * 8) ^ ((vrow & 3) << 3);
        const float* src = kv + (((size_t)(b * Sc + s0 + sc0) * 2 + 1) * Hc + h) * Dc + vrow;
        #pragma unroll
        for (int j = 0; j < 8; ++j) o[j] = (__bf16)src[(size_t)j * 2 * Hc * Dc];
    }
    *(bf8_t*)dst = o;
}

// Kernel 1: flash-attention over a tile-sliced key range; fixed-max softmax
// (m=8) makes split-S partials pure sums. Tiles staged via global_load_lds
// into a 3-deep LDS ring: ONE barrier per tile, counted vmcnt(4).
__global__ __launch_bounds__(256, 4)
void fa_part(const float* __restrict__ q,
             const __bf16* __restrict__ kvb,
             const int* __restrict__ kpm,
             const int* __restrict__ causal_p,
             float* __restrict__ out,        // used when split_shift==0
             float* __restrict__ part_o,
             float* __restrict__ part_l,
             int split_shift)
{
    __shared__ __bf16 shKV[3 * TILE_H];
    __shared__ __bf16 Ps[4][16][LDP];

    const int tid  = threadIdx.x;
    const int wave = tid >> 6;
    const int lane = tid & 63;
    const int n16  = lane & 15;
    const int quad = lane >> 4;

    // decode: h in low 3 bits (XCD locality), reversed qt (big blocks first)
    const int bid = blockIdx.x;
    const int h   = bid & 7;
    const int g   = bid >> 3;
    const int b   = g >> (5 + split_shift);
    const int idx = g & ((nQB << split_shift) - 1);
    const int s   = idx & ((1 << split_shift) - 1);
    const int qt  = nQB - 1 - (idx >> split_shift);
    const int q_base = qt * BQ;
    const int causal = causal_p[0];

    // ---- Q fragments (A-layout: m=lane&15, k=quad*8+j), scale folded in ----
    const float scale = 0.125f;
    const int trow = q_base + wave * 16 + n16;
    bf8_t a_q[2];
    {
        const float* qrow = q + ((size_t)(b * Tc + trow) * Hc + h) * Dc;
        #pragma unroll
        for (int f = 0; f < 2; ++f) {
            const float4 x0 = *(const float4*)(qrow + f * 32 + quad * 8);
            const float4 x1 = *(const float4*)(qrow + f * 32 + quad * 8 + 4);
            bf8_t v;
            v[0] = (__bf16)(x0.x * scale); v[1] = (__bf16)(x0.y * scale);
            v[2] = (__bf16)(x0.z * scale); v[3] = (__bf16)(x0.w * scale);
            v[4] = (__bf16)(x1.x * scale); v[5] = (__bf16)(x1.y * scale);
            v[6] = (__bf16)(x1.z * scale); v[7] = (__bf16)(x1.w * scale);
            a_q[f] = v;
        }
    }

    f4_t o_acc[4];
    #pragma unroll
    for (int dt = 0; dt < 4; ++dt) o_acc[dt] = (f4_t){0.f, 0.f, 0.f, 0.f};
    float l_r[4] = {0.f, 0.f, 0.f, 0.f};

    const int kend = causal ? (q_base + BQ) : Sc;
    const int ntot = kend / BK;
    const int t0   = (ntot * s)       >> split_shift;
    const int t1   = (ntot * (s + 1)) >> split_shift;

    const __bf16* kvt = kvb + (size_t)((b * Hc + h) * NKT) * TILE_H;
    const int* kpm_b  = kpm + b * Sc;

    // swizzled LDS read offsets (halves), loop-invariant
    const int kA    = n16 * 64 + ((quad * 8) ^ ((n16 & 7) << 3));
    const int kA2   = kA ^ 32;
    const int vA    = 2048 + n16 * 32 + ((quad * 8) ^ ((n16 & 3) << 3));
    const int sbase = wave * 512 + lane * 8;
    const int tq    = q_base + wave * 16 + quad * 4;

    int cur = 0, nxt = TILE_H, nn = 2 * TILE_H;
    int cmA = 0, cmB = 0;
    if (t0 < t1) {   // prologue: stage first tile of this slice
        const __bf16* src = kvt + (size_t)t0 * TILE_H;
        g2l16(src + sbase,        &shKV[wave * 512]);
        g2l16(src + 2048 + sbase, &shKV[2048 + wave * 512]);
        cmA = kpm_b[t0 * BK + n16];
        cmB = kpm_b[t0 * BK + 16 + n16];
    }

    for (int it = t0; it < t1; ++it) {
        const int kb = it * BK;
        int nmA = 0, nmB = 0;
        if (it + 1 < t1) {   // stage next tile into ring; keep it in flight
            const __bf16* src = kvt + (size_t)(it + 1) * TILE_H;
            g2l16(src + sbase,        &shKV[nxt + wave * 512]);
            g2l16(src + 2048 + sbase, &shKV[nxt + 2048 + wave * 512]);
            nmA = kpm_b[kb + BK + n16];
            nmB = kpm_b[kb + BK + 16 + n16];
            asm volatile("s_waitcnt vmcnt(4)" ::: "memory");  // cur tile landed
        } else {
            asm volatile("s_waitcnt vmcnt(0)" ::: "memory");
        }
        __builtin_amdgcn_s_barrier();
        asm volatile("" ::: "memory");

        // ---- QK^T + fixed-max softmax (m = 8) ----
        #pragma unroll
        for (int sub = 0; sub < 2; ++sub) {
            const bf8_t bk0 = *(const bf8_t*)&shKV[cur + sub * 1024 + kA];
            const bf8_t bk1 = *(const bf8_t*)&shKV[cur + sub * 1024 + kA2];
            f4_t acc = (f4_t){0.f, 0.f, 0.f, 0.f};
            acc = __builtin_amdgcn_mfma_f32_16x16x32_bf16(a_q[0], bk0, acc, 0, 0, 0);
            acc = __builtin_amdgcn_mfma_f32_16x16x32_bf16(a_q[1], bk1, acc, 0, 0, 0);
            const int key = kb + sub * 16 + n16;
            const bool kvalid = (sub ? cmB : cmA) != 0;
            #pragma unroll
            for (int r = 0; r < 4; ++r) {
                const bool valid = kvalid && (!causal || key <= tq + r);
                const float p = valid ? __expf(acc[r] - 8.0f) : 0.0f;
                l_r[r] += p;
                Ps[wave][quad * 4 + r][sub * 16 + n16] = (__bf16)p;
            }
        }

        // within-wave LDS RAW: P C-layout store before A-layout reload
        asm volatile("s_waitcnt lgkmcnt(0)" ::: "memory");

        // ---- PV (V^T, swizzled) ----
        const bf8_t a_p = *(const bf8_t*)&Ps[wave][n16][quad * 8];
        #pragma unroll
        for (int dt = 0; dt < 4; ++dt) {
            const bf8_t b_v = *(const bf8_t*)&shKV[cur + vA + dt * 512];
            o_acc[dt] = __builtin_amdgcn_mfma_f32_16x16x32_bf16(a_p, b_v, o_acc[dt], 0, 0, 0);
        }

        const int tswap = cur; cur = nxt; nxt = nn; nn = tswap;
        cmA = nmA; cmB = nmB;
    }

    // ---- row-sum reduction across the quad's 16 lanes ----
    #pragma unroll
    for (int off = 1; off < 16; off <<= 1) {
        #pragma unroll
        for (int r = 0; r < 4; ++r) l_r[r] += __shfl_xor(l_r[r], off, 16);
    }

    if (split_shift == 0) {
        float inv_l[4];
        #pragma unroll
        for (int r = 0; r < 4; ++r) inv_l[r] = 1.0f / l_r[r];
        #pragma unroll
        for (int dt = 0; dt < 4; ++dt) {
            #pragma unroll
            for (int r = 0; r < 4; ++r) {
                const int t = q_base + wave * 16 + quad * 4 + r;
                out[((size_t)(b * Tc + t) * Hc + h) * Dc + dt * 16 + n16] =
                    o_acc[dt][r] * inv_l[r];
            }
        }
    } else {
        const int qi = (b * Hc + h) * nQB + qt;
        float* po = part_o + ((size_t)(qi << split_shift) + s) * (BQ * Dc);
        #pragma unroll
        for (int dt = 0; dt < 4; ++dt) {
            #pragma unroll
            for (int r = 0; r < 4; ++r) {
                const int row = wave * 16 + quad * 4 + r;
                po[row * Dc + dt * 16 + n16] = o_acc[dt][r];
            }
        }
        if (n16 == 0) {
            #pragma unroll
            for (int r = 0; r < 4; ++r) {
                const int row = wave * 16 + quad * 4 + r;
                part_l[((size_t)(qi << split_shift) + s) * BQ + row] = l_r[r];
            }
        }
    }
}

// Kernel 2: sum partials across splits, normalize, scatter to out layout.
__global__ __launch_bounds__(256, 4)
void fa_reduce(const float* __restrict__ part_o,
               const float* __restrict__ part_l,
               float* __restrict__ out,
               int split_shift)
{
    const int gtid = blockIdx.x * 256 + threadIdx.x;     // one float4 each
    const int e    = gtid & (BQ * Dc / 4 - 1);           // 0..1023
    const int qi   = gtid >> 10;
    const int row  = e >> 4;
    const int d4   = e & 15;
    const int SPLIT = 1 << split_shift;

    float4 acc = make_float4(0.f, 0.f, 0.f, 0.f);
    float  l   = 0.f;
    for (int s = 0; s < SPLIT; ++s) {
        const size_t pi = (size_t)(qi << split_shift) + s;
        const float4 v = *(const float4*)(part_o + pi * (BQ * Dc) + row * Dc + d4 * 4);
        acc.x += v.x; acc.y += v.y; acc.z += v.z; acc.w += v.w;
        l += part_l[pi * BQ + row];
    }
    const float inv = 1.0f / l;
    const int qt = qi & (nQB - 1);
    const int h  = (qi / nQB) & (Hc - 1);
    const int b  = qi / (nQB * Hc);
    const int t  = qt * BQ + row;
    float4 o;
    o.x = acc.x * inv; o.y = acc.y * inv; o.z = acc.z * inv; o.w = acc.w * inv;
    *(float4*)(out + ((size_t)(b * Tc + t) * Hc + h) * Dc + d4 * 4) = o;
}

extern "C" void kernel_launch(void* const* d_in, const int* in_sizes, int n_in,
                              void* d_out, int out_size, void* d_ws, size_t ws_size,
                              hipStream_t stream) {
    const float* q   = (const float*)d_in[0];
    const float* kv  = (const float*)d_in[1];
    const int*   kpm = (const int*)d_in[2];
    const int*   cz  = (const int*)d_in[3];
    float*       out = (float*)d_out;

    __bf16* kvb = (__bf16*)d_ws;
    const size_t kvb_bytes = (size_t)Bc * Hc * NKT * TILE_H * sizeof(__bf16); // 8 MB
    float* part_o = (float*)((char*)d_ws + kvb_bytes);

    const size_t nQT = (size_t)Bc * Hc * nQB;                 // 512 q-tiles
    auto ws_need = [&](int split) {
        return kvb_bytes + nQT * split * (size_t)(BQ * Dc + BQ) * sizeof(float);
    };
    int ss = 2;                                               // SPLIT=4
    if (ws_size < ws_need(4)) ss = (ws_size >= ws_need(2)) ? 1 : 0;
    const int SPLIT = 1 << ss;
    float* part_l = part_o + nQT * SPLIT * (BQ * Dc);

    const int grid0 = Bc * Hc * NKT * 512 / 256;              // 2048
    fa_prep<<<grid0, 256, 0, stream>>>(kv, kvb);

    const int grid1 = Bc * Hc * nQB * SPLIT;
    fa_part<<<grid1, 256, 0, stream>>>(q, kvb, kpm, cz, out, part_o, part_l, ss);
    if (ss > 0) {
        const int grid2 = (int)(nQT * (BQ * Dc / 4) / 256);   // 2048
        fa_reduce<<<grid2, 256, 0, stream>>>(part_o, part_l, out, ss);
    }
}